// Round 5
// baseline (184.013 us; speedup 1.0000x reference)
//
#include <hip/hip_runtime.h>
#include <hip/hip_fp16.h>
#include <math.h>

#define NFEAT 128
#define NCLS  64
#define RQ8   8             // uint4 per fp16 64-wide row (128 B)
#define WSTR  132           // W LDS row stride in halves
#define NBLK  256           // grid for edge-stream passes
#define BSLACK 8192         // per-bucket csr slack (need <=3840: 256 rows x <=15)

// ---------- helpers ----------

typedef _Float16 h2v __attribute__((ext_vector_type(2)));

__device__ __forceinline__ float dot2acc(unsigned int hv, unsigned int wv, float c) {
#if __has_builtin(__builtin_amdgcn_fdot2)
    union { unsigned int u; h2v v; } a, bq; a.u = hv; bq.u = wv;
    return __builtin_amdgcn_fdot2(a.v, bq.v, c, false);
#else
    union { unsigned int u; __half2 h; } a, bq; a.u = hv; bq.u = wv;
    float2 fa = __half22float2(a.h), fb = __half22float2(bq.h);
    return fmaf(fa.x, fb.x, fmaf(fa.y, fb.y, c));
#endif
}

// packed fp16 accumulate: 4 v_pk_add_f16 per 16B row-chunk
__device__ __forceinline__ void acc4(__half2 a[4], uint4 v) {
    union { uint4 u; __half2 h[4]; } c; c.u = v;
    a[0] = __hadd2(a[0], c.h[0]); a[1] = __hadd2(a[1], c.h[1]);
    a[2] = __hadd2(a[2], c.h[2]); a[3] = __hadd2(a[3], c.h[3]);
}

__device__ __forceinline__ __half2 red8(__half2 a) {   // reduce across 8 sub-slots
    union { __half2 h; int i; } u, v;
    u.h = a; v.i = __shfl_xor(u.i, 8);  a = __hadd2(a, v.h);
    u.h = a; v.i = __shfl_xor(u.i, 16); a = __hadd2(a, v.h);
    u.h = a; v.i = __shfl_xor(u.i, 32); a = __hadd2(a, v.h);
    return a;
}

// block-wide (256 thr) exclusive scan via wave shfl; scratch >= 8 ints; 3 barriers
__device__ __forceinline__ int block_excl_scan_256(int v, int tid, int* scratch, int* total) {
    const int lane = tid & 63, wv = tid >> 6;
    __syncthreads();                               // protect scratch reuse
    int x = v;
    #pragma unroll
    for (int off = 1; off < 64; off <<= 1) {
        int y = __shfl_up(x, off);
        if (lane >= off) x += y;
    }
    if (lane == 63) scratch[wv] = x;
    __syncthreads();
    if (wv == 0 && lane < 4) {
        int t = scratch[lane];
        int y = __shfl_up(t, 1); if (lane >= 1) t += y;
        y = __shfl_up(t, 2);     if (lane >= 2) t += y;
        scratch[4 + lane] = t;                     // inclusive wave-prefix
    }
    __syncthreads();
    int wbase = (wv == 0) ? 0 : scratch[4 + wv - 1];
    if (total) *total = scratch[7];
    return wbase + x - v;                          // exclusive prefix of v
}

// ---------- build pass 1: 256-node-bucket histogram (LDS atomics) ----------
__global__ __launch_bounds__(256) void hist_kernel(const int* __restrict__ dst,
                                                   int* __restrict__ h,
                                                   int E4, int E, int nb) {
    __shared__ int lh[256];
    const int tid = threadIdx.x;
    lh[tid] = 0;
    __syncthreads();
    for (int idx = blockIdx.x * 256 + tid; idx < E4; idx += NBLK * 256) {
        int base = idx * 4;
        if (base + 3 < E) {
            int4 d = ((const int4*)dst)[idx];
            atomicAdd(&lh[d.x >> 8], 1); atomicAdd(&lh[d.y >> 8], 1);
            atomicAdd(&lh[d.z >> 8], 1); atomicAdd(&lh[d.w >> 8], 1);
        } else {
            for (int e = base; e < E; ++e) atomicAdd(&lh[dst[e] >> 8], 1);
        }
    }
    __syncthreads();
    if (tid < nb) h[blockIdx.x * nb + tid] = lh[tid];
}

// pass 2: per bucket, exclusive scan over its 256 block-counts + total
__global__ __launch_bounds__(256) void colscan_kernel(int* __restrict__ h,
                                                      int* __restrict__ btot, int nb) {
    __shared__ int scratch[8];
    const int tid = threadIdx.x;
    const int B = blockIdx.x;
    int v = h[tid * nb + B];
    int tot;
    int pre = block_excl_scan_256(v, tid, scratch, &tot);
    h[tid * nb + B] = pre;                         // exclusive within bucket
    if (tid == 0) btot[B] = tot;
}

// pass 3: replay edges, write packed (src<<8 | dst&255) into bucket-ordered COO.
__global__ __launch_bounds__(256) void bucket_scatter_kernel(const int* __restrict__ src,
                                                             const int* __restrict__ dst,
                                                             const int* __restrict__ h,
                                                             const int* __restrict__ btot,
                                                             unsigned int* __restrict__ bedg,
                                                             int E4, int E, int nb) {
    __shared__ int cur[256];
    __shared__ int scratch[8];
    const int tid = threadIdx.x;
    int bt = (tid < nb) ? btot[tid] : 0;
    int pre = block_excl_scan_256(bt, tid, scratch, nullptr);
    if (tid < nb) cur[tid] = pre + h[blockIdx.x * nb + tid];
    __syncthreads();
    for (int idx = blockIdx.x * 256 + tid; idx < E4; idx += NBLK * 256) {
        int base = idx * 4;
        if (base + 3 < E) {
            int4 s = ((const int4*)src)[idx];
            int4 d = ((const int4*)dst)[idx];
            int p;
            p = atomicAdd(&cur[d.x >> 8], 1); bedg[p] = ((unsigned)s.x << 8) | (d.x & 255);
            p = atomicAdd(&cur[d.y >> 8], 1); bedg[p] = ((unsigned)s.y << 8) | (d.y & 255);
            p = atomicAdd(&cur[d.z >> 8], 1); bedg[p] = ((unsigned)s.z << 8) | (d.z & 255);
            p = atomicAdd(&cur[d.w >> 8], 1); bedg[p] = ((unsigned)s.w << 8) | (d.w & 255);
        } else {
            for (int e = base; e < E; ++e) {
                int p = atomicAdd(&cur[dst[e] >> 8], 1);
                bedg[p] = ((unsigned)src[e] << 8) | (dst[e] & 255);
            }
        }
    }
}

// pass 4: per-bucket LDS counting sort -> TWO-SEGMENT csr rows per node:
// seg0 = sources < halfN (+self if i<halfN), seg1 = sources >= halfN (+self else),
// each padded x8 with dummy row N. rbeg/rmid/rend, dinv.
__global__ __launch_bounds__(256) void drain_kernel(const unsigned int* __restrict__ bedg,
                                                    const int* __restrict__ btot,
                                                    int* __restrict__ csr,
                                                    int* __restrict__ rbeg,
                                                    int* __restrict__ rmid,
                                                    int* __restrict__ rend,
                                                    float* __restrict__ dinv,
                                                    int N, int nb, int halfN) {
    __shared__ int lcnt0[256];
    __shared__ int lcnt1[256];
    __shared__ int scratch[8];
    __shared__ int s0_s, s1_s;
    const int B = blockIdx.x;
    const int tid = threadIdx.x;

    int bt = (tid < nb) ? btot[tid] : 0;
    int pre = block_excl_scan_256(bt, tid, scratch, nullptr);
    if (tid == B) { s0_s = pre; s1_s = pre + bt; }
    lcnt0[tid] = 0; lcnt1[tid] = 0;
    __syncthreads();
    const int s0 = s0_s, s1 = s1_s;

    for (int e = s0 + tid; e < s1; e += 256) {
        unsigned int Ev = bedg[e];
        int d = Ev & 255u;
        if ((int)(Ev >> 8) < halfN) atomicAdd(&lcnt0[d], 1);
        else                        atomicAdd(&lcnt1[d], 1);
    }
    __syncthreads();

    const int i = B * 256 + tid;
    const bool valid = (i < N);
    const int c0 = lcnt0[tid], c1 = lcnt1[tid];
    const bool selfLo = (i < halfN);
    const int cp0 = valid ? (((c0 + (selfLo ? 1 : 0)) + 7) & ~7) : 0;
    const int cp1 = valid ? (((c1 + (selfLo ? 0 : 1)) + 7) & ~7) : 0;
    int rpre = block_excl_scan_256(cp0 + cp1, tid, scratch, nullptr);
    const int start = s0 + BSLACK * B + rpre;
    __syncthreads();
    lcnt0[tid] = start;                            // cursor seg0
    lcnt1[tid] = start + cp0;                      // cursor seg1
    __syncthreads();

    for (int e = s0 + tid; e < s1; e += 256) {
        unsigned int Ev = bedg[e];
        int d = Ev & 255u, s = (int)(Ev >> 8);
        int p = atomicAdd((s < halfN) ? &lcnt0[d] : &lcnt1[d], 1);
        csr[p] = s;
    }
    __syncthreads();

    if (valid) {
        int st = start;
        int mid = st + cp0, end = mid + cp1;
        int q0 = lcnt0[tid];                       // == st + c0
        if (selfLo) csr[q0++] = i;                 // self entry in its half
        for (int p = q0; p < mid; ++p) csr[p] = N;
        int q1 = lcnt1[tid];                       // == mid + c1
        if (!selfLo) csr[q1++] = i;
        for (int p = q1; p < end; ++p) csr[p] = N;
        rbeg[i] = st; rmid[i] = mid; rend[i] = end;
        dinv[i] = rsqrtf((float)(c0 + c1) + 1.0f); // +1 self-loop
    }
}

// ---------- projection first (SGC linearity): zh = fp16(dinv_i * (x_i @ W^T)) ----------
__global__ __launch_bounds__(512) void gemm_kernel(const float* __restrict__ x,
                                                   const float* __restrict__ W,
                                                   const float* __restrict__ dinv,
                                                   __half* __restrict__ zh,
                                                   __half* __restrict__ y1h, int N) {
    __shared__ __half Wl[NCLS * WSTR];
    __shared__ __align__(16) __half HT[64][NFEAT];

    const int tid = threadIdx.x;
    const int w = tid >> 6, lane = tid & 63;

    if (blockIdx.x == 0 && tid < 32) {             // zero dummy rows (row N, 16 uint2 each)
        if (tid < 16) ((uint2*)zh)[(size_t)N * 16 + tid] = uint2{0u, 0u};
        else          ((uint2*)y1h)[(size_t)N * 16 + (tid - 16)] = uint2{0u, 0u};
    }

    for (int e = tid; e < NCLS * NFEAT; e += 512) {
        int r = e >> 7, c = e & 127;
        Wl[r * WSTR + c] = __float2half(W[e]);
    }
    {
        const float4* srcf = (const float4*)(x + (size_t)blockIdx.x * 64 * NFEAT);
        uint2* dh = (uint2*)&HT[0][0];
        const int row0 = blockIdx.x * 64;
        #pragma unroll
        for (int t = 0; t < 4; ++t) {
            int e = tid + 512 * t;                 // float4 index, 2048 total (32 per row)
            float4 f = (row0 + (e >> 5) < N) ? srcf[e] : float4{0.f, 0.f, 0.f, 0.f};
            union { uint2 u; __half2 h[2]; } r;
            r.h[0] = __floats2half2_rn(f.x, f.y);
            r.h[1] = __floats2half2_rn(f.z, f.w);
            dh[e] = r.u;
        }
    }
    __syncthreads();

    unsigned int wreg[64];
    {
        const uint2* wr = (const uint2*)&Wl[lane * WSTR];
        #pragma unroll
        for (int t = 0; t < 32; ++t) {
            uint2 v = wr[t];
            wreg[2 * t] = v.x; wreg[2 * t + 1] = v.y;
        }
    }

    #pragma unroll 1
    for (int r = 0; r < 8; ++r) {
        int node = blockIdx.x * 64 + w * 8 + r;
        if (node >= N) break;
        const unsigned int* hrow = (const unsigned int*)&HT[w * 8 + r][0];
        float dot = 0.f;
        #pragma unroll
        for (int t = 0; t < 64; ++t)
            dot = dot2acc(hrow[t], wreg[t], dot);
        zh[(size_t)node * NCLS + lane] = __float2half(dinv[node] * dot);
    }
}

// ---------- gather core: 64-wide rows, 8 subs x 8 q, 32-edge main loop ----------
// All csr reads fully guarded within [ks, ke) (segment length is a multiple of 8).
__device__ __forceinline__ void gather_row64(__half2 a[4], const uint4* __restrict__ X,
                                             const int* __restrict__ csr,
                                             int ks, int ke, int sub, int q, int Nd) {
    int k = ks;
    int j0, j1, j2, j3;
    bool have = (k + 32 <= ke);
    if (have) {
        j0 = csr[k + sub];      j1 = csr[k + 8 + sub];
        j2 = csr[k + 16 + sub]; j3 = csr[k + 24 + sub];
    }
    while (have) {
        uint4 v0 = X[(size_t)j0 * RQ8 + q];
        uint4 v1 = X[(size_t)j1 * RQ8 + q];
        uint4 v2 = X[(size_t)j2 * RQ8 + q];
        uint4 v3 = X[(size_t)j3 * RQ8 + q];
        k += 32;
        have = (k + 32 <= ke);
        if (have) {                               // prefetch next indices
            j0 = csr[k + sub];      j1 = csr[k + 8 + sub];
            j2 = csr[k + 16 + sub]; j3 = csr[k + 24 + sub];
        }
        acc4(a, v0); acc4(a, v1); acc4(a, v2); acc4(a, v3);
    }
    int rem = (ke - k) >> 3;                      // 0..3 rounds of 8, wave-uniform
    if (rem) {
        int t0 = csr[k + sub];
        int t1 = (rem >= 2) ? csr[k + 8 + sub]  : Nd;   // guarded: no overrun reads
        int t2 = (rem >= 3) ? csr[k + 16 + sub] : Nd;
        uint4 v0 = X[(size_t)t0 * RQ8 + q];
        uint4 v1 = X[(size_t)t1 * RQ8 + q];
        uint4 v2 = X[(size_t)t2 * RQ8 + q];
        acc4(a, v0); acc4(a, v1); acc4(a, v2);
    }
}

// ---------- hop pass-lo: partial_i = red8(sum over seg0), fp16 lossless ----------
__global__ __launch_bounds__(256) void hop_lo_kernel(const __half* __restrict__ in_h,
                                                     const int* __restrict__ rbeg,
                                                     const int* __restrict__ rmid,
                                                     const int* __restrict__ csr,
                                                     __half* __restrict__ part, int N) {
    const int tid = threadIdx.x;
    const int w = tid >> 6, lane = tid & 63;
    const int i = blockIdx.x * 4 + w;
    if (i >= N) return;                           // wave-uniform; no barriers
    const int sub = lane >> 3;
    const int q = lane & 7;
    const uint4* X = (const uint4*)in_h;

    __half2 a[4];
    a[0] = __float2half2_rn(0.f); a[1] = a[0]; a[2] = a[0]; a[3] = a[0];

    gather_row64(a, X, csr, rbeg[i], rmid[i], sub, q, N);

    a[0] = red8(a[0]); a[1] = red8(a[1]); a[2] = red8(a[2]); a[3] = red8(a[3]);

    if (sub == 0) {
        union { uint4 u; __half2 h[4]; } r;
        r.h[0] = a[0]; r.h[1] = a[1]; r.h[2] = a[2]; r.h[3] = a[3];
        ((uint4*)part)[(size_t)i * RQ8 + q] = r.u;
    }
}

// ---------- hop1 pass-hi: y1 = fp16( dinv^2 * (partial + sum over seg1) ) ----------
__global__ __launch_bounds__(256) void hop1_hi_kernel(const __half* __restrict__ in_h,
                                                      const __half* __restrict__ part,
                                                      const float* __restrict__ dinv,
                                                      const int* __restrict__ rmid,
                                                      const int* __restrict__ rend,
                                                      const int* __restrict__ csr,
                                                      __half* __restrict__ out_h, int N) {
    const int tid = threadIdx.x;
    const int w = tid >> 6, lane = tid & 63;
    const int i = blockIdx.x * 4 + w;
    if (i >= N) return;
    const int sub = lane >> 3;
    const int q = lane & 7;
    const uint4* X = (const uint4*)in_h;

    __half2 a[4];
    if (sub == 0) {                               // seed with partial (counted once in red8)
        union { uint4 u; __half2 h[4]; } c;
        c.u = ((const uint4*)part)[(size_t)i * RQ8 + q];
        a[0] = c.h[0]; a[1] = c.h[1]; a[2] = c.h[2]; a[3] = c.h[3];
    } else {
        a[0] = __float2half2_rn(0.f); a[1] = a[0]; a[2] = a[0]; a[3] = a[0];
    }

    gather_row64(a, X, csr, rmid[i], rend[i], sub, q, N);

    a[0] = red8(a[0]); a[1] = red8(a[1]); a[2] = red8(a[2]); a[3] = red8(a[3]);

    if (sub == 0) {
        float di = dinv[i];
        float s = di * di;
        union { uint4 u; __half2 h[4]; } r;
        #pragma unroll
        for (int t = 0; t < 4; ++t) {
            float2 f = __half22float2(a[t]);
            r.h[t] = __floats2half2_rn(s * f.x, s * f.y);
        }
        ((uint4*)out_h)[(size_t)i * RQ8 + q] = r.u;
    }
}

// ---------- hop2 pass-hi fused with bias + log_softmax: out fp32 [N,64] ----------
__global__ __launch_bounds__(256) void hop2cls_hi_kernel(const __half* __restrict__ in_h,
                                                         const __half* __restrict__ part,
                                                         const float* __restrict__ dinv,
                                                         const int* __restrict__ rmid,
                                                         const int* __restrict__ rend,
                                                         const int* __restrict__ csr,
                                                         const float* __restrict__ b,
                                                         float* __restrict__ out, int N) {
    const int tid = threadIdx.x;
    const int w = tid >> 6, lane = tid & 63;
    const int i = blockIdx.x * 4 + w;
    if (i >= N) return;
    const int sub = lane >> 3;
    const int q = lane & 7;
    const uint4* X = (const uint4*)in_h;

    float4 b0 = ((const float4*)b)[q * 2];
    float4 b1 = ((const float4*)b)[q * 2 + 1];

    __half2 a[4];
    if (sub == 0) {                               // seed with partial
        union { uint4 u; __half2 h[4]; } c;
        c.u = ((const uint4*)part)[(size_t)i * RQ8 + q];
        a[0] = c.h[0]; a[1] = c.h[1]; a[2] = c.h[2]; a[3] = c.h[3];
    } else {
        a[0] = __float2half2_rn(0.f); a[1] = a[0]; a[2] = a[0]; a[3] = a[0];
    }

    gather_row64(a, X, csr, rmid[i], rend[i], sub, q, N);

    a[0] = red8(a[0]); a[1] = red8(a[1]); a[2] = red8(a[2]); a[3] = red8(a[3]);

    if (sub == 0) {                                  // lanes 0..7 hold the 64-class row
        float di = dinv[i];
        float f[8];
        float2 p;
        p = __half22float2(a[0]); f[0] = fmaf(di, p.x, b0.x); f[1] = fmaf(di, p.y, b0.y);
        p = __half22float2(a[1]); f[2] = fmaf(di, p.x, b0.z); f[3] = fmaf(di, p.y, b0.w);
        p = __half22float2(a[2]); f[4] = fmaf(di, p.x, b1.x); f[5] = fmaf(di, p.y, b1.y);
        p = __half22float2(a[3]); f[6] = fmaf(di, p.x, b1.z); f[7] = fmaf(di, p.y, b1.w);
        float m = f[0];
        #pragma unroll
        for (int t = 1; t < 8; ++t) m = fmaxf(m, f[t]);
        m = fmaxf(m, __shfl_xor(m, 1));              // partners stay within lanes 0..7
        m = fmaxf(m, __shfl_xor(m, 2));
        m = fmaxf(m, __shfl_xor(m, 4));
        float se = 0.f;
        #pragma unroll
        for (int t = 0; t < 8; ++t) se += __expf(f[t] - m);
        se += __shfl_xor(se, 1);
        se += __shfl_xor(se, 2);
        se += __shfl_xor(se, 4);
        float ls = m + logf(se);
        float4 o0 = {f[0] - ls, f[1] - ls, f[2] - ls, f[3] - ls};
        float4 o1 = {f[4] - ls, f[5] - ls, f[6] - ls, f[7] - ls};
        float4* op = (float4*)(out + (size_t)i * NCLS);
        op[q * 2] = o0; op[q * 2 + 1] = o1;
    }
}

// ---------- launch ----------

static inline size_t align256(size_t v) { return (v + 255) & ~(size_t)255; }

extern "C" void kernel_launch(void* const* d_in, const int* in_sizes, int n_in,
                              void* d_out, int out_size, void* d_ws, size_t ws_size,
                              hipStream_t stream) {
    const float* x  = (const float*)d_in[0];
    const int*   ei = (const int*)d_in[1];
    const float* W  = (const float*)d_in[2];
    const float* b  = (const float*)d_in[3];
    float* out = (float*)d_out;

    const int N = in_sizes[0] / NFEAT;   // 50000
    const int E = in_sizes[1] / 2;       // 800000
    const int* src = ei;
    const int* dst = ei + E;
    const int NBUCK = (N + 255) >> 8;    // 196 buckets of 256 nodes
    const int halfN = (N + 1) >> 1;      // 25000: source-blocking split point

    const int CSR_CAP = E + BSLACK * NBUCK + 64;

    char* ws = (char*)d_ws;
    size_t o = 0;
    int*          h     = (int*)(ws + o);          o += align256((size_t)NBLK * NBUCK * 4);
    int*          btot  = (int*)(ws + o);          o += align256(256 * 4);
    unsigned int* bedg  = (unsigned int*)(ws + o); o += align256((size_t)E * 4);
    int*          csr   = (int*)(ws + o);          o += align256((size_t)CSR_CAP * 4);
    int*          rbeg  = (int*)(ws + o);          o += align256((size_t)N * 4);
    int*          rmid  = (int*)(ws + o);          o += align256((size_t)N * 4);
    int*          rend  = (int*)(ws + o);          o += align256((size_t)N * 4);
    float*        dinv  = (float*)(ws + o);        o += align256((size_t)N * 4);
    __half*       zh    = (__half*)(ws + o);       o += align256((size_t)(N + 1) * NCLS * 2);
    __half*       y1h   = (__half*)(ws + o);       o += align256((size_t)(N + 1) * NCLS * 2);
    __half*       part  = (__half*)(ws + o);       o += align256((size_t)N * NCLS * 2);

    const int E4 = (E + 3) / 4;
    const int HG = (N + 3) / 4;

    hist_kernel<<<NBLK, 256, 0, stream>>>(dst, h, E4, E, NBUCK);
    colscan_kernel<<<NBUCK, 256, 0, stream>>>(h, btot, NBUCK);
    bucket_scatter_kernel<<<NBLK, 256, 0, stream>>>(src, dst, h, btot, bedg, E4, E, NBUCK);
    drain_kernel<<<NBUCK, 256, 0, stream>>>(bedg, btot, csr, rbeg, rmid, rend, dinv,
                                            N, NBUCK, halfN);
    gemm_kernel<<<(N + 63) / 64, 512, 0, stream>>>(x, W, dinv, zh, y1h, N);
    hop_lo_kernel<<<HG, 256, 0, stream>>>(zh, rbeg, rmid, csr, part, N);
    hop1_hi_kernel<<<HG, 256, 0, stream>>>(zh, part, dinv, rmid, rend, csr, y1h, N);
    hop_lo_kernel<<<HG, 256, 0, stream>>>(y1h, rbeg, rmid, csr, part, N);
    hop2cls_hi_kernel<<<HG, 256, 0, stream>>>(y1h, part, dinv, rmid, rend, csr, b, out, N);
}

// Round 6
// 154.513 us; speedup vs baseline: 1.1909x; 1.1909x over previous
//
#include <hip/hip_runtime.h>
#include <hip/hip_fp16.h>
#include <math.h>

#define NFEAT 128
#define NCLS  64
#define RQ8   8             // uint4 per fp16 64-wide row (128 B)
#define WSTR  132           // W LDS row stride in halves
#define NBLK  256           // grid for edge-stream passes
#define BSLACK 2048         // per-bucket csr slack: 256 rows x (self + <=7 pads)

// ---------- helpers ----------

typedef _Float16 h2v __attribute__((ext_vector_type(2)));

__device__ __forceinline__ float dot2acc(unsigned int hv, unsigned int wv, float c) {
#if __has_builtin(__builtin_amdgcn_fdot2)
    union { unsigned int u; h2v v; } a, bq; a.u = hv; bq.u = wv;
    return __builtin_amdgcn_fdot2(a.v, bq.v, c, false);
#else
    union { unsigned int u; __half2 h; } a, bq; a.u = hv; bq.u = wv;
    float2 fa = __half22float2(a.h), fb = __half22float2(bq.h);
    return fmaf(fa.x, fb.x, fmaf(fa.y, fb.y, c));
#endif
}

// packed fp16 accumulate: 4 v_pk_add_f16 per 16B row-chunk
__device__ __forceinline__ void acc4(__half2 a[4], uint4 v) {
    union { uint4 u; __half2 h[4]; } c; c.u = v;
    a[0] = __hadd2(a[0], c.h[0]); a[1] = __hadd2(a[1], c.h[1]);
    a[2] = __hadd2(a[2], c.h[2]); a[3] = __hadd2(a[3], c.h[3]);
}

__device__ __forceinline__ __half2 red8(__half2 a) {   // reduce across 8 sub-slots
    union { __half2 h; int i; } u, v;
    u.h = a; v.i = __shfl_xor(u.i, 8);  a = __hadd2(a, v.h);
    u.h = a; v.i = __shfl_xor(u.i, 16); a = __hadd2(a, v.h);
    u.h = a; v.i = __shfl_xor(u.i, 32); a = __hadd2(a, v.h);
    return a;
}

// block-wide (256 thr) exclusive scan via wave shfl; scratch >= 8 ints; 3 barriers
__device__ __forceinline__ int block_excl_scan_256(int v, int tid, int* scratch, int* total) {
    const int lane = tid & 63, wv = tid >> 6;
    __syncthreads();                               // protect scratch reuse
    int x = v;
    #pragma unroll
    for (int off = 1; off < 64; off <<= 1) {
        int y = __shfl_up(x, off);
        if (lane >= off) x += y;
    }
    if (lane == 63) scratch[wv] = x;
    __syncthreads();
    if (wv == 0 && lane < 4) {
        int t = scratch[lane];
        int y = __shfl_up(t, 1); if (lane >= 1) t += y;
        y = __shfl_up(t, 2);     if (lane >= 2) t += y;
        scratch[4 + lane] = t;                     // inclusive wave-prefix
    }
    __syncthreads();
    int wbase = (wv == 0) ? 0 : scratch[4 + wv - 1];
    if (total) *total = scratch[7];
    return wbase + x - v;                          // exclusive prefix of v
}

// ---------- build pass 1: 256-node-bucket histogram (LDS atomics) ----------
__global__ __launch_bounds__(256) void hist_kernel(const int* __restrict__ dst,
                                                   int* __restrict__ h,
                                                   int E4, int E, int nb) {
    __shared__ int lh[256];
    const int tid = threadIdx.x;
    lh[tid] = 0;
    __syncthreads();
    for (int idx = blockIdx.x * 256 + tid; idx < E4; idx += NBLK * 256) {
        int base = idx * 4;
        if (base + 3 < E) {
            int4 d = ((const int4*)dst)[idx];
            atomicAdd(&lh[d.x >> 8], 1); atomicAdd(&lh[d.y >> 8], 1);
            atomicAdd(&lh[d.z >> 8], 1); atomicAdd(&lh[d.w >> 8], 1);
        } else {
            for (int e = base; e < E; ++e) atomicAdd(&lh[dst[e] >> 8], 1);
        }
    }
    __syncthreads();
    if (tid < nb) h[blockIdx.x * nb + tid] = lh[tid];
}

// pass 2: per bucket, exclusive scan over its 256 block-counts + total
__global__ __launch_bounds__(256) void colscan_kernel(int* __restrict__ h,
                                                      int* __restrict__ btot, int nb) {
    __shared__ int scratch[8];
    const int tid = threadIdx.x;
    const int B = blockIdx.x;
    int v = h[tid * nb + B];
    int tot;
    int pre = block_excl_scan_256(v, tid, scratch, &tot);
    h[tid * nb + B] = pre;                         // exclusive within bucket
    if (tid == 0) btot[B] = tot;
}

// pass 3: replay edges, write packed (src<<8 | dst&255) into bucket-ordered COO.
__global__ __launch_bounds__(256) void bucket_scatter_kernel(const int* __restrict__ src,
                                                             const int* __restrict__ dst,
                                                             const int* __restrict__ h,
                                                             const int* __restrict__ btot,
                                                             unsigned int* __restrict__ bedg,
                                                             int E4, int E, int nb) {
    __shared__ int cur[256];
    __shared__ int scratch[8];
    const int tid = threadIdx.x;
    int bt = (tid < nb) ? btot[tid] : 0;
    int pre = block_excl_scan_256(bt, tid, scratch, nullptr);
    if (tid < nb) cur[tid] = pre + h[blockIdx.x * nb + tid];
    __syncthreads();
    for (int idx = blockIdx.x * 256 + tid; idx < E4; idx += NBLK * 256) {
        int base = idx * 4;
        if (base + 3 < E) {
            int4 s = ((const int4*)src)[idx];
            int4 d = ((const int4*)dst)[idx];
            int p;
            p = atomicAdd(&cur[d.x >> 8], 1); bedg[p] = ((unsigned)s.x << 8) | (d.x & 255);
            p = atomicAdd(&cur[d.y >> 8], 1); bedg[p] = ((unsigned)s.y << 8) | (d.y & 255);
            p = atomicAdd(&cur[d.z >> 8], 1); bedg[p] = ((unsigned)s.z << 8) | (d.z & 255);
            p = atomicAdd(&cur[d.w >> 8], 1); bedg[p] = ((unsigned)s.w << 8) | (d.w & 255);
        } else {
            for (int e = base; e < E; ++e) {
                int p = atomicAdd(&cur[dst[e] >> 8], 1);
                bedg[p] = ((unsigned)src[e] << 8) | (dst[e] & 255);
            }
        }
    }
}

// pass 4: per-bucket LDS counting sort -> csr rows (self baked in, padded x8, pads = N),
// rbeg/rend, dinv. Bucket edge range + csr base recomputed locally from btot.
__global__ __launch_bounds__(256) void drain_kernel(const unsigned int* __restrict__ bedg,
                                                    const int* __restrict__ btot,
                                                    int* __restrict__ csr,
                                                    int* __restrict__ rbeg,
                                                    int* __restrict__ rend,
                                                    float* __restrict__ dinv,
                                                    int N, int nb) {
    __shared__ int lcnt[256];
    __shared__ int loc[256];
    __shared__ int scratch[8];
    __shared__ int s0_s, s1_s;
    const int B = blockIdx.x;
    const int tid = threadIdx.x;

    int bt = (tid < nb) ? btot[tid] : 0;
    int pre = block_excl_scan_256(bt, tid, scratch, nullptr);
    if (tid == B) { s0_s = pre; s1_s = pre + bt; }
    lcnt[tid] = 0;
    __syncthreads();
    const int s0 = s0_s, s1 = s1_s;

    for (int e = s0 + tid; e < s1; e += 256)
        atomicAdd(&lcnt[bedg[e] & 255u], 1);
    __syncthreads();

    const int c = lcnt[tid];
    const int cp = (c + 8) & ~7;                   // +1 self, padded to x8
    int rpre = block_excl_scan_256(cp, tid, scratch, nullptr);
    const int base = s0 + BSLACK * B;              // csr region for this bucket
    loc[tid] = base + rpre;                        // row start
    __syncthreads();
    lcnt[tid] = loc[tid];                          // reuse as cursor
    __syncthreads();

    for (int e = s0 + tid; e < s1; e += 256) {
        unsigned int Ev = bedg[e];
        int p = atomicAdd(&lcnt[Ev & 255u], 1);
        csr[p] = (int)(Ev >> 8);
    }
    __syncthreads();

    int i = B * 256 + tid;
    if (i < N) {
        int start = loc[tid], end = start + cp;
        int q = lcnt[tid];                         // == start + c
        csr[q++] = i;                              // self entry baked into row
        for (int p = q; p < end; ++p) csr[p] = N;  // <=7 pads (dummy row)
        rbeg[i] = start; rend[i] = end;
        dinv[i] = rsqrtf((float)c + 1.0f);         // +1 self-loop
    }
}

// ---------- projection first (SGC linearity): zh = fp16(dinv_i * (x_i @ W^T)) ----------
__global__ __launch_bounds__(512) void gemm_kernel(const float* __restrict__ x,
                                                   const float* __restrict__ W,
                                                   const float* __restrict__ dinv,
                                                   __half* __restrict__ zh,
                                                   __half* __restrict__ y1h, int N) {
    __shared__ __half Wl[NCLS * WSTR];
    __shared__ __align__(16) __half HT[64][NFEAT];

    const int tid = threadIdx.x;
    const int w = tid >> 6, lane = tid & 63;

    if (blockIdx.x == 0 && tid < 32) {             // zero dummy rows (row N, 16 uint2 each)
        if (tid < 16) ((uint2*)zh)[(size_t)N * 16 + tid] = uint2{0u, 0u};
        else          ((uint2*)y1h)[(size_t)N * 16 + (tid - 16)] = uint2{0u, 0u};
    }

    for (int e = tid; e < NCLS * NFEAT; e += 512) {
        int r = e >> 7, c = e & 127;
        Wl[r * WSTR + c] = __float2half(W[e]);
    }
    {
        const float4* srcf = (const float4*)(x + (size_t)blockIdx.x * 64 * NFEAT);
        uint2* dh = (uint2*)&HT[0][0];
        const int row0 = blockIdx.x * 64;
        #pragma unroll
        for (int t = 0; t < 4; ++t) {
            int e = tid + 512 * t;                 // float4 index, 2048 total (32 per row)
            float4 f = (row0 + (e >> 5) < N) ? srcf[e] : float4{0.f, 0.f, 0.f, 0.f};
            union { uint2 u; __half2 h[2]; } r;
            r.h[0] = __floats2half2_rn(f.x, f.y);
            r.h[1] = __floats2half2_rn(f.z, f.w);
            dh[e] = r.u;
        }
    }
    __syncthreads();

    unsigned int wreg[64];
    {
        const uint2* wr = (const uint2*)&Wl[lane * WSTR];
        #pragma unroll
        for (int t = 0; t < 32; ++t) {
            uint2 v = wr[t];
            wreg[2 * t] = v.x; wreg[2 * t + 1] = v.y;
        }
    }

    #pragma unroll 1
    for (int r = 0; r < 8; ++r) {
        int node = blockIdx.x * 64 + w * 8 + r;
        if (node >= N) break;
        const unsigned int* hrow = (const unsigned int*)&HT[w * 8 + r][0];
        float dot = 0.f;
        #pragma unroll
        for (int t = 0; t < 64; ++t)
            dot = dot2acc(hrow[t], wreg[t], dot);
        zh[(size_t)node * NCLS + lane] = __float2half(dinv[node] * dot);
    }
}

// ---------- dual-row gather: 2 rows x 2 chunks = 4 idx + 4 gathers in flight ----------
// All csr reads wave-uniformly guarded (row length is a multiple of 8; k steps by 16,
// so k < ke implies k+8 <= ke). Exhausted rows/chunks redirect to zeroed dummy row Nd.
__device__ __forceinline__ void gather_dual(__half2 a0[4], __half2 a1[4],
                                            const uint4* __restrict__ X,
                                            const int* __restrict__ csr,
                                            int k0, int ke0, int k1, int ke1,
                                            int sub, int q, int Nd) {
    int j00 = (k0     < ke0) ? csr[k0 + sub]     : Nd;
    int j01 = (k0 + 8 < ke0) ? csr[k0 + 8 + sub] : Nd;
    int j10 = (k1     < ke1) ? csr[k1 + sub]     : Nd;
    int j11 = (k1 + 8 < ke1) ? csr[k1 + 8 + sub] : Nd;
    while (k0 < ke0 || k1 < ke1) {
        uint4 v00 = X[(size_t)j00 * RQ8 + q];
        uint4 v01 = X[(size_t)j01 * RQ8 + q];
        uint4 v10 = X[(size_t)j10 * RQ8 + q];
        uint4 v11 = X[(size_t)j11 * RQ8 + q];
        k0 += 16; k1 += 16;
        j00 = (k0     < ke0) ? csr[k0 + sub]     : Nd;   // prefetch next chunk idx
        j01 = (k0 + 8 < ke0) ? csr[k0 + 8 + sub] : Nd;
        j10 = (k1     < ke1) ? csr[k1 + sub]     : Nd;
        j11 = (k1 + 8 < ke1) ? csr[k1 + 8 + sub] : Nd;
        acc4(a0, v00); acc4(a0, v01);                    // dead chunks add exact zeros
        acc4(a1, v10); acc4(a1, v11);
    }
}

// ---------- hop1: out[i] = fp16( dinv_i^2 * sum_{j in row(i)} in[j] ), 2 rows/wave ----------
__global__ __launch_bounds__(256) void hop64_dual_kernel(const __half* __restrict__ in_h,
                                                         const float* __restrict__ dinv,
                                                         const int* __restrict__ rbeg,
                                                         const int* __restrict__ rend,
                                                         const int* __restrict__ csr,
                                                         __half* __restrict__ out_h, int N) {
    const int tid = threadIdx.x;
    const int w = tid >> 6, lane = tid & 63;
    const int i0 = (blockIdx.x * 4 + w) * 2;
    if (i0 >= N) return;                          // wave-uniform; no barriers
    const int i1 = i0 + 1;
    const bool has1 = (i1 < N);
    const int sub = lane >> 3;
    const int q = lane & 7;
    const uint4* X = (const uint4*)in_h;

    __half2 a0[4], a1[4];
    a0[0] = __float2half2_rn(0.f); a0[1] = a0[0]; a0[2] = a0[0]; a0[3] = a0[0];
    a1[0] = a0[0]; a1[1] = a0[0]; a1[2] = a0[0]; a1[3] = a0[0];

    int ks0 = rbeg[i0], ke0 = rend[i0];
    int ks1 = has1 ? rbeg[i1] : 0, ke1 = has1 ? rend[i1] : 0;
    gather_dual(a0, a1, X, csr, ks0, ke0, ks1, ke1, sub, q, N);

    a0[0] = red8(a0[0]); a0[1] = red8(a0[1]); a0[2] = red8(a0[2]); a0[3] = red8(a0[3]);
    a1[0] = red8(a1[0]); a1[1] = red8(a1[1]); a1[2] = red8(a1[2]); a1[3] = red8(a1[3]);

    if (sub == 0) {
        {
            float di = dinv[i0];
            float s = di * di;
            union { uint4 u; __half2 h[4]; } r;
            #pragma unroll
            for (int t = 0; t < 4; ++t) {
                float2 f = __half22float2(a0[t]);
                r.h[t] = __floats2half2_rn(s * f.x, s * f.y);
            }
            ((uint4*)out_h)[(size_t)i0 * RQ8 + q] = r.u;
        }
        if (has1) {
            float di = dinv[i1];
            float s = di * di;
            union { uint4 u; __half2 h[4]; } r;
            #pragma unroll
            for (int t = 0; t < 4; ++t) {
                float2 f = __half22float2(a1[t]);
                r.h[t] = __floats2half2_rn(s * f.x, s * f.y);
            }
            ((uint4*)out_h)[(size_t)i1 * RQ8 + q] = r.u;
        }
    }
}

// ---------- hop2 fused with bias + log_softmax, 2 rows/wave: out fp32 [N,64] ----------
__device__ __forceinline__ void cls_epilogue(__half2 a[4], float di, float4 b0, float4 b1,
                                             float* __restrict__ out, int node, int q) {
    float f[8];
    float2 p;
    p = __half22float2(a[0]); f[0] = fmaf(di, p.x, b0.x); f[1] = fmaf(di, p.y, b0.y);
    p = __half22float2(a[1]); f[2] = fmaf(di, p.x, b0.z); f[3] = fmaf(di, p.y, b0.w);
    p = __half22float2(a[2]); f[4] = fmaf(di, p.x, b1.x); f[5] = fmaf(di, p.y, b1.y);
    p = __half22float2(a[3]); f[6] = fmaf(di, p.x, b1.z); f[7] = fmaf(di, p.y, b1.w);
    float m = f[0];
    #pragma unroll
    for (int t = 1; t < 8; ++t) m = fmaxf(m, f[t]);
    m = fmaxf(m, __shfl_xor(m, 1));                  // partners stay within lanes 0..7
    m = fmaxf(m, __shfl_xor(m, 2));
    m = fmaxf(m, __shfl_xor(m, 4));
    float se = 0.f;
    #pragma unroll
    for (int t = 0; t < 8; ++t) se += __expf(f[t] - m);
    se += __shfl_xor(se, 1);
    se += __shfl_xor(se, 2);
    se += __shfl_xor(se, 4);
    float ls = m + logf(se);
    float4 o0 = {f[0] - ls, f[1] - ls, f[2] - ls, f[3] - ls};
    float4 o1 = {f[4] - ls, f[5] - ls, f[6] - ls, f[7] - ls};
    float4* op = (float4*)(out + (size_t)node * NCLS);
    op[q * 2] = o0; op[q * 2 + 1] = o1;
}

__global__ __launch_bounds__(256) void hop2cls_dual_kernel(const __half* __restrict__ in_h,
                                                           const float* __restrict__ dinv,
                                                           const int* __restrict__ rbeg,
                                                           const int* __restrict__ rend,
                                                           const int* __restrict__ csr,
                                                           const float* __restrict__ b,
                                                           float* __restrict__ out, int N) {
    const int tid = threadIdx.x;
    const int w = tid >> 6, lane = tid & 63;
    const int i0 = (blockIdx.x * 4 + w) * 2;
    if (i0 >= N) return;
    const int i1 = i0 + 1;
    const bool has1 = (i1 < N);
    const int sub = lane >> 3;
    const int q = lane & 7;
    const uint4* X = (const uint4*)in_h;

    float4 b0 = ((const float4*)b)[q * 2];
    float4 b1 = ((const float4*)b)[q * 2 + 1];

    __half2 a0[4], a1[4];
    a0[0] = __float2half2_rn(0.f); a0[1] = a0[0]; a0[2] = a0[0]; a0[3] = a0[0];
    a1[0] = a0[0]; a1[1] = a0[0]; a1[2] = a0[0]; a1[3] = a0[0];

    int ks0 = rbeg[i0], ke0 = rend[i0];
    int ks1 = has1 ? rbeg[i1] : 0, ke1 = has1 ? rend[i1] : 0;
    gather_dual(a0, a1, X, csr, ks0, ke0, ks1, ke1, sub, q, N);

    a0[0] = red8(a0[0]); a0[1] = red8(a0[1]); a0[2] = red8(a0[2]); a0[3] = red8(a0[3]);
    a1[0] = red8(a1[0]); a1[1] = red8(a1[1]); a1[2] = red8(a1[2]); a1[3] = red8(a1[3]);

    if (sub == 0) {
        cls_epilogue(a0, dinv[i0], b0, b1, out, i0, q);
        if (has1) cls_epilogue(a1, dinv[i1], b0, b1, out, i1, q);
    }
}

// ---------- launch ----------

static inline size_t align256(size_t v) { return (v + 255) & ~(size_t)255; }

extern "C" void kernel_launch(void* const* d_in, const int* in_sizes, int n_in,
                              void* d_out, int out_size, void* d_ws, size_t ws_size,
                              hipStream_t stream) {
    const float* x  = (const float*)d_in[0];
    const int*   ei = (const int*)d_in[1];
    const float* W  = (const float*)d_in[2];
    const float* b  = (const float*)d_in[3];
    float* out = (float*)d_out;

    const int N = in_sizes[0] / NFEAT;   // 50000
    const int E = in_sizes[1] / 2;       // 800000
    const int* src = ei;
    const int* dst = ei + E;
    const int NBUCK = (N + 255) >> 8;    // 196 buckets of 256 nodes

    const int CSR_CAP = E + BSLACK * NBUCK + 64;   // pads/self slack + overrun slack

    char* ws = (char*)d_ws;
    size_t o = 0;
    int*          h     = (int*)(ws + o);          o += align256((size_t)NBLK * NBUCK * 4);
    int*          btot  = (int*)(ws + o);          o += align256(256 * 4);
    unsigned int* bedg  = (unsigned int*)(ws + o); o += align256((size_t)E * 4);
    int*          csr   = (int*)(ws + o);          o += align256((size_t)CSR_CAP * 4);
    int*          rbeg  = (int*)(ws + o);          o += align256((size_t)N * 4);
    int*          rend  = (int*)(ws + o);          o += align256((size_t)N * 4);
    float*        dinv  = (float*)(ws + o);        o += align256((size_t)N * 4);
    __half*       zh    = (__half*)(ws + o);       o += align256((size_t)(N + 1) * NCLS * 2);
    __half*       y1h   = (__half*)(ws + o);       o += align256((size_t)(N + 1) * NCLS * 2);

    const int E4 = (E + 3) / 4;
    const int HG = (N + 7) / 8;          // 2 rows per wave, 4 waves per block

    hist_kernel<<<NBLK, 256, 0, stream>>>(dst, h, E4, E, NBUCK);
    colscan_kernel<<<NBUCK, 256, 0, stream>>>(h, btot, NBUCK);
    bucket_scatter_kernel<<<NBLK, 256, 0, stream>>>(src, dst, h, btot, bedg, E4, E, NBUCK);
    drain_kernel<<<NBUCK, 256, 0, stream>>>(bedg, btot, csr, rbeg, rend, dinv, N, NBUCK);
    gemm_kernel<<<(N + 63) / 64, 512, 0, stream>>>(x, W, dinv, zh, y1h, N);
    hop64_dual_kernel<<<HG, 256, 0, stream>>>(zh, dinv, rbeg, rend, csr, y1h, N);
    hop2cls_dual_kernel<<<HG, 256, 0, stream>>>(y1h, dinv, rbeg, rend, csr, b, out, N);
}